// Round 15
// baseline (253.619 us; speedup 1.0000x reference)
//
#include <hip/hip_runtime.h>
#include <hip/hip_bf16.h>
#include <stdint.h>

typedef __bf16 bf16_8 __attribute__((ext_vector_type(8)));
typedef float f32_4 __attribute__((ext_vector_type(4)));
typedef short short4v __attribute__((ext_vector_type(4)));

#define VMCNT(n) asm volatile("s_waitcnt vmcnt(" #n ")" ::: "memory")
#define SBAR __builtin_amdgcn_s_barrier()
#define SCHB __builtin_amdgcn_sched_barrier(0)

static __device__ __forceinline__ unsigned short f2bf(float f) {
    union { float f; unsigned int u; } v; v.f = f;
    unsigned int u = v.u;
    unsigned int r = (u + 0x7fffu + ((u >> 16) & 1u)) >> 16;
    return (unsigned short)r;
}

static __device__ __forceinline__ unsigned int pack_bf16x2(float a, float b) {
    union { float f; unsigned int u; } ua, ub;
    ua.f = a; ub.f = b;
    return __builtin_amdgcn_perm(ub.u + 0x8000u, ua.u + 0x8000u, 0x07060302u);
}

// 16x16x16 bf16 MFMA; B-operand layout == 16x16x32 C-layout (S^T feeds PV).
static __device__ __forceinline__ f32_4 mfma_16x16x16_bf16(short4v a, short4v b, f32_4 c) {
#if __has_builtin(__builtin_amdgcn_mfma_f32_16x16x16bf16_1k)
    return __builtin_amdgcn_mfma_f32_16x16x16bf16_1k(a, b, c, 0, 0, 0);
#else
    asm volatile("v_mfma_f32_16x16x16_bf16 %0, %1, %2, %0"
                 : "+v"(c) : "v"(a), "v"(b));
    return c;
#endif
}

// async global -> LDS, 16 B per lane (lds dest = wave-uniform base + lane*16)
static __device__ __forceinline__ void gll16(const unsigned short* g, unsigned short* l) {
    __builtin_amdgcn_global_load_lds(
        (const __attribute__((address_space(1))) unsigned int*)g,
        (__attribute__((address_space(3))) unsigned int*)l, 16, 0, 0);
}

// ---------------- fused prep: cvt x + transpose both weight matrices -------
__global__ __launch_bounds__(256) void prep_kernel(
    const float* __restrict__ x, unsigned int* __restrict__ xbf,
    const float* __restrict__ w_qkv, unsigned short* __restrict__ wqkvt,
    const float* __restrict__ w_proj, unsigned short* __restrict__ wprojt) {
    __shared__ unsigned short tile[64][65];
    int bid = blockIdx.x;
    if (bid < 8192) {
        int i = bid * 256 + threadIdx.x;
        float4 f = ((const float4*)x)[i];
        uint2 o;
        o.x = pack_bf16x2(f.x, f.y);
        o.y = pack_bf16x2(f.z, f.w);
        ((uint2*)xbf)[i] = o;
        return;
    }
    const float* in; unsigned short* out; int N, bx, by;
    if (bid < 8960) {
        in = w_qkv; out = wqkvt; N = 3072;
        int t = bid - 8192; bx = t % 48; by = t / 48;
    } else {
        in = w_proj; out = wprojt; N = 1024;
        int t = bid - 8960; bx = t & 15; by = t >> 4;
    }
    const int K = 1024;
    int k0 = by * 64, n0 = bx * 64;
    int tc = threadIdx.x & 63, tr = threadIdx.x >> 6;
    for (int p = 0; p < 16; ++p) {
        int k = p * 4 + tr;
        tile[k][tc] = f2bf(in[(size_t)(k0 + k) * N + n0 + tc]);
    }
    __syncthreads();
    for (int p = 0; p < 16; ++p) {
        int n = p * 4 + tr;
        out[(size_t)(n0 + n) * K + k0 + tc] = tile[tc][n];
    }
}

#define QSCALE 0.1803368801111204f  // 0.125 * log2(e)
#define BK 64

// ---------------- QKV GEMM: BM=256 BN=128 BK=64, 3-ring, 1 barrier/iter ----
// r13 verbatim (measured 65.5-72.5us across runs, 786 TF best).
__global__ __launch_bounds__(512) void gemm_qkv(
    const unsigned short* __restrict__ A,
    const unsigned short* __restrict__ Bt,
    const float* __restrict__ bias,
    int M, int N, int K,
    unsigned short* __restrict__ q_out, unsigned short* __restrict__ k_out,
    unsigned short* __restrict__ v_out) {
    __shared__ __align__(16) unsigned short As[3][256 * 64];
    __shared__ __align__(16) unsigned short Bs[3][128 * 64];
    int tid = threadIdx.x;
    int wave = tid >> 6, lane = tid & 63;
    int wm = wave >> 1, wn = wave & 1;
    int quad = lane >> 4, l16 = lane & 15;
    int m0 = blockIdx.y * 256, n0 = blockIdx.x * 128;
    int which = n0 >> 10;  // 0=Q 1=K 2=V

    f32_4 acc[4][4] = {};

    int srow = lane >> 3;                  // 0..7
    int scs = ((lane & 7) ^ srow) * 8;     // swizzled chunk elem offset
    const unsigned short* Ag = A + (size_t)(m0 + wave * 32 + srow) * K + scs;
    const unsigned short* Bg = Bt + (size_t)(n0 + wave * 16 + srow) * K + scs;
    int sx = l16 & 7;

    unsigned short *a0 = As[0], *a1 = As[1], *a2 = As[2];
    unsigned short *b0 = Bs[0], *b1 = Bs[1], *b2 = Bs[2];

#define STG_A(dst, kc) do { \
        for (int g = 0; g < 4; ++g) \
            gll16(Ag + (kc) + (size_t)(g * 8) * K, (dst) + (wave * 32 + g * 8) * 64); \
    } while (0)
#define STG_B(dst, kc) do { \
        for (int g = 0; g < 2; ++g) \
            gll16(Bg + (kc) + (size_t)(g * 8) * K, (dst) + (wave * 16 + g * 8) * 64); \
    } while (0)

    // prologue: stage tiles 0 and 1 (12 loads; tile0's 6 are the oldest)
    STG_A(a0, 0); STG_B(b0, 0);
    STG_A(a1, 64); STG_B(b1, 64);

    const int nkt = K >> 6;  // 16
    for (int kt = 0; kt < nkt; ++kt) {
        if (kt + 1 < nkt) { VMCNT(6); } else { VMCNT(0); }
        SCHB; SBAR; SCHB;   // single publish point per K-tile

        // ---- phase 0 (ks=0) ----
        bf16_8 af[4], bfr[4];
        for (int i = 0; i < 4; ++i)
            af[i] = *(const bf16_8*)(a0 + (wm * 64 + i * 16 + l16) * 64 +
                                     ((unsigned)(quad ^ sx)) * 8);
        for (int j = 0; j < 4; ++j)
            bfr[j] = *(const bf16_8*)(b0 + (wn * 64 + j * 16 + l16) * 64 +
                                      ((unsigned)(quad ^ sx)) * 8);
        if (kt + 2 < nkt) STG_A(a2, (kt + 2) * 64);
        __builtin_amdgcn_s_setprio(1);
        if (which < 2) {
            for (int i = 0; i < 4; ++i)
                for (int j = 0; j < 4; ++j)
                    acc[i][j] = __builtin_amdgcn_mfma_f32_16x16x32_bf16(bfr[j], af[i], acc[i][j], 0, 0, 0);
        } else {
            for (int i = 0; i < 4; ++i)
                for (int j = 0; j < 4; ++j)
                    acc[i][j] = __builtin_amdgcn_mfma_f32_16x16x32_bf16(af[i], bfr[j], acc[i][j], 0, 0, 0);
        }
        __builtin_amdgcn_s_setprio(0);

        // ---- phase 1 (ks=1) ----
        for (int i = 0; i < 4; ++i)
            af[i] = *(const bf16_8*)(a0 + (wm * 64 + i * 16 + l16) * 64 +
                                     ((unsigned)((4 + quad) ^ sx)) * 8);
        for (int j = 0; j < 4; ++j)
            bfr[j] = *(const bf16_8*)(b0 + (wn * 64 + j * 16 + l16) * 64 +
                                      ((unsigned)((4 + quad) ^ sx)) * 8);
        if (kt + 2 < nkt) STG_B(b2, (kt + 2) * 64);
        __builtin_amdgcn_s_setprio(1);
        if (which < 2) {
            for (int i = 0; i < 4; ++i)
                for (int j = 0; j < 4; ++j)
                    acc[i][j] = __builtin_amdgcn_mfma_f32_16x16x32_bf16(bfr[j], af[i], acc[i][j], 0, 0, 0);
        } else {
            for (int i = 0; i < 4; ++i)
                for (int j = 0; j < 4; ++j)
                    acc[i][j] = __builtin_amdgcn_mfma_f32_16x16x32_bf16(af[i], bfr[j], acc[i][j], 0, 0, 0);
        }
        __builtin_amdgcn_s_setprio(0);

        unsigned short* t;
        t = a0; a0 = a1; a1 = a2; a2 = t;
        t = b0; b0 = b1; b1 = b2; b2 = t;
    }
#undef STG_A
#undef STG_B

    int b = m0 >> 11;
    int tbase = (m0 & 2047) + wm * 64;
    int nw0 = n0 + wn * 64;
    if (which < 2) {
        unsigned short* dst = which == 0 ? q_out : k_out;
        float scale = which == 0 ? QSCALE : 1.0f;
        int h0 = ((n0 & 1023) >> 6) + wn;
        size_t base = ((size_t)((b << 4) + h0) * 2048) * 64;
        for (int j = 0; j < 4; ++j) {
            float4 b4 = *(const float4*)(bias + nw0 + j * 16 + quad * 4);
            int d0 = j * 16 + quad * 4;
            for (int i = 0; i < 4; ++i) {
                int t = tbase + i * 16 + l16;
                uint2 pk;
                pk.x = pack_bf16x2((acc[i][j][0] + b4.x) * scale,
                                   (acc[i][j][1] + b4.y) * scale);
                pk.y = pack_bf16x2((acc[i][j][2] + b4.z) * scale,
                                   (acc[i][j][3] + b4.w) * scale);
                *(uint2*)(dst + base + (size_t)t * 64 + d0) = pk;
            }
        }
    } else {
        for (int j = 0; j < 4; ++j) {
            int n = nw0 + j * 16 + l16;
            int c = n & 1023, h = c >> 6, d = c & 63;
            float bs = bias[n];
            size_t base = ((size_t)((b << 4) + h) * 64 + d) * 2048;
            for (int i = 0; i < 4; ++i) {
                int t0 = tbase + i * 16 + quad * 4;
                uint2 pk;
                pk.x = pack_bf16x2(acc[i][j][0] + bs, acc[i][j][1] + bs);
                pk.y = pack_bf16x2(acc[i][j][2] + bs, acc[i][j][3] + bs);
                *(uint2*)(v_out + base + t0) = pk;
            }
        }
    }
}

// ---------------- proj GEMM: BM=256 BN=128 BK=64, 3-ring, 1 barrier/iter ---
// Ported onto the qkv loop (measured 786 TF on identical workload shape).
// K-loop byte-identical to qkv's which==2 branch; epilogue = measured r2
// proj formula with wm=wave>>1 (m-offset<=192<256), wn=wave&1 (n<128).
// grid MUST be (N/128, M/256) = (8, 32). Indexing re-audited r14/r15.
__global__ __launch_bounds__(512) void gemm_proj(
    const unsigned short* __restrict__ A,
    const unsigned short* __restrict__ Bt,
    const float* __restrict__ bias,
    int M, int N, int K, float* __restrict__ outf) {
    __shared__ __align__(16) unsigned short As[3][256 * 64];
    __shared__ __align__(16) unsigned short Bs[3][128 * 64];
    int tid = threadIdx.x;
    int wave = tid >> 6, lane = tid & 63;
    int wm = wave >> 1, wn = wave & 1;
    int quad = lane >> 4, l16 = lane & 15;
    int m0 = blockIdx.y * 256, n0 = blockIdx.x * 128;

    f32_4 acc[4][4] = {};

    int srow = lane >> 3;
    int scs = ((lane & 7) ^ srow) * 8;
    const unsigned short* Ag = A + (size_t)(m0 + wave * 32 + srow) * K + scs;
    const unsigned short* Bg = Bt + (size_t)(n0 + wave * 16 + srow) * K + scs;
    int sx = l16 & 7;

    unsigned short *a0 = As[0], *a1 = As[1], *a2 = As[2];
    unsigned short *b0 = Bs[0], *b1 = Bs[1], *b2 = Bs[2];

#define STG_A(dst, kc) do { \
        for (int g = 0; g < 4; ++g) \
            gll16(Ag + (kc) + (size_t)(g * 8) * K, (dst) + (wave * 32 + g * 8) * 64); \
    } while (0)
#define STG_B(dst, kc) do { \
        for (int g = 0; g < 2; ++g) \
            gll16(Bg + (kc) + (size_t)(g * 8) * K, (dst) + (wave * 16 + g * 8) * 64); \
    } while (0)

    STG_A(a0, 0); STG_B(b0, 0);
    STG_A(a1, 64); STG_B(b1, 64);

    const int nkt = K >> 6;  // 16
    for (int kt = 0; kt < nkt; ++kt) {
        if (kt + 1 < nkt) { VMCNT(6); } else { VMCNT(0); }
        SCHB; SBAR; SCHB;

        // ---- phase 0 (ks=0) ----
        bf16_8 af[4], bfr[4];
        for (int i = 0; i < 4; ++i)
            af[i] = *(const bf16_8*)(a0 + (wm * 64 + i * 16 + l16) * 64 +
                                     ((unsigned)(quad ^ sx)) * 8);
        for (int j = 0; j < 4; ++j)
            bfr[j] = *(const bf16_8*)(b0 + (wn * 64 + j * 16 + l16) * 64 +
                                      ((unsigned)(quad ^ sx)) * 8);
        if (kt + 2 < nkt) STG_A(a2, (kt + 2) * 64);
        __builtin_amdgcn_s_setprio(1);
        for (int i = 0; i < 4; ++i)
            for (int j = 0; j < 4; ++j)
                acc[i][j] = __builtin_amdgcn_mfma_f32_16x16x32_bf16(af[i], bfr[j], acc[i][j], 0, 0, 0);
        __builtin_amdgcn_s_setprio(0);

        // ---- phase 1 (ks=1) ----
        for (int i = 0; i < 4; ++i)
            af[i] = *(const bf16_8*)(a0 + (wm * 64 + i * 16 + l16) * 64 +
                                     ((unsigned)((4 + quad) ^ sx)) * 8);
        for (int j = 0; j < 4; ++j)
            bfr[j] = *(const bf16_8*)(b0 + (wn * 64 + j * 16 + l16) * 64 +
                                      ((unsigned)((4 + quad) ^ sx)) * 8);
        if (kt + 2 < nkt) STG_B(b2, (kt + 2) * 64);
        __builtin_amdgcn_s_setprio(1);
        for (int i = 0; i < 4; ++i)
            for (int j = 0; j < 4; ++j)
                acc[i][j] = __builtin_amdgcn_mfma_f32_16x16x32_bf16(af[i], bfr[j], acc[i][j], 0, 0, 0);
        __builtin_amdgcn_s_setprio(0);

        unsigned short* t;
        t = a0; a0 = a1; a1 = a2; a2 = t;
        t = b0; b0 = b1; b1 = b2; b2 = t;
    }
#undef STG_A
#undef STG_B

    for (int j = 0; j < 4; ++j) {
        int n = n0 + wn * 64 + j * 16 + l16;
        float bs = bias[n];
        for (int i = 0; i < 4; ++i) {
            int m = m0 + wm * 64 + i * 16 + quad * 4;
            for (int r = 0; r < 4; ++r)
                outf[(size_t)(m + r) * N + n] = acc[i][j][r] + bs;
        }
    }
}

// ---------------- flash attention: single 64-row tile/block, 5 blocks/CU ---
// r8 + T5 setprio (ran+passed r9/r11/r12/r13).
__global__ __launch_bounds__(256, 5) void attn_kernel(
    const unsigned short* __restrict__ Q, const unsigned short* __restrict__ Kb,
    const unsigned short* __restrict__ Vt, unsigned short* __restrict__ Y,
    int T) {
    __shared__ __align__(16) unsigned short KsB[2][64 * 64];
    __shared__ __align__(16) unsigned short VtsB[2][64 * 64];

    int tid = threadIdx.x;
    int wave = tid >> 6, lane = tid & 63;
    int quad = lane >> 4, l16 = lane & 15;
    int bh = blockIdx.x;
    int b = bh >> 4, h = bh & 15;
    int qt = 31 - blockIdx.y;
    int qw = qt * 64 + wave * 16;
    int nkt = qt + 1;

    int srow = lane >> 3;
    int scs = ((lane & 7) ^ srow) * 8;
    int sx = l16 & 7;

    // Q fragments: q = l16 (B-operand compatible), d = ks*32+quad*8
    bf16_8 qa[2];
    for (int ks = 0; ks < 2; ++ks)
        qa[ks] = *(const bf16_8*)(Q + ((size_t)bh * T + qw + l16) * 64 + ks * 32 + quad * 8);

    f32_4 o[4] = {};    // [df]: d = df*16+quad*4+r, q = l16
    f32_4 osum = {};    // lsum via ones-MFMA: all 4 regs identical
    short4v vones;
    { unsigned short one = 0x3F80;
      vones[0] = (short)one; vones[1] = (short)one; vones[2] = (short)one; vones[3] = (short)one; }

    // stage tile 0 into buffer 0 (async, swizzled)
    for (int p = 0; p < 2; ++p) {
        int row = wave * 16 + p * 8;
        gll16(Kb + ((size_t)bh * T + row + srow) * 64 + scs, &KsB[0][row * 64]);
        gll16(Vt + ((size_t)bh * 64 + row + srow) * (size_t)T + scs, &VtsB[0][row * 64]);
    }
    __syncthreads();

    for (int kt = 0; kt < nkt; ++kt) {
        int cur = kt & 1;
        int kb = kt * 64;
        if (kt + 1 < nkt) {
            int kb2 = kb + 64, nxt = cur ^ 1;
            for (int p = 0; p < 2; ++p) {
                int row = wave * 16 + p * 8;
                gll16(Kb + ((size_t)bh * T + kb2 + row + srow) * 64 + scs, &KsB[nxt][row * 64]);
                gll16(Vt + ((size_t)bh * 64 + row + srow) * (size_t)T + kb2 + scs, &VtsB[nxt][row * 64]);
            }
        }
        const unsigned short* KsC = KsB[cur];
        const unsigned short* VtsC = VtsB[cur];

        // S^T = K @ Q^T : lane holds (k = kf*16+quad*4+r, q = l16)
        f32_4 s[4] = {};
        __builtin_amdgcn_s_setprio(1);
        for (int kf = 0; kf < 4; ++kf) {
            bf16_8 k0 = *(const bf16_8*)(KsC + (kf * 16 + l16) * 64 + ((unsigned)(quad ^ sx)) * 8);
            bf16_8 k1 = *(const bf16_8*)(KsC + (kf * 16 + l16) * 64 + ((unsigned)((4 + quad) ^ sx)) * 8);
            s[kf] = __builtin_amdgcn_mfma_f32_16x16x32_bf16(k0, qa[0], s[kf], 0, 0, 0);
            s[kf] = __builtin_amdgcn_mfma_f32_16x16x32_bf16(k1, qa[1], s[kf], 0, 0, 0);
        }
        __builtin_amdgcn_s_setprio(0);

        // causal mask (diagonal tile only)
        if (kt == qt) {
            int q = qw + l16;
            for (int kf = 0; kf < 4; ++kf) {
                int kk = kb + kf * 16 + quad * 4;
                for (int r = 0; r < 4; ++r)
                    if (kk + r > q) s[kf][r] = -1e30f;
            }
        }

        // no-max softmax: p = 2^s, packed in-register to PV B-operands
        short4v pb[4];
        for (int kf = 0; kf < 4; ++kf) {
            float p0 = __builtin_amdgcn_exp2f(s[kf][0]);
            float p1 = __builtin_amdgcn_exp2f(s[kf][1]);
            float p2 = __builtin_amdgcn_exp2f(s[kf][2]);
            float p3 = __builtin_amdgcn_exp2f(s[kf][3]);
            union { unsigned int u[2]; short4v s4; } pu;
            pu.u[0] = pack_bf16x2(p0, p1);
            pu.u[1] = pack_bf16x2(p2, p3);
            pb[kf] = pu.s4;
        }

        // PV + lsum: o[df] += V^T@P^T ; osum += 1@P^T (rowsum, no shuffles)
        __builtin_amdgcn_s_setprio(1);
        for (int kf = 0; kf < 4; ++kf) {
            osum = mfma_16x16x16_bf16(vones, pb[kf], osum);
            unsigned voff = ((unsigned)((2 * kf + (quad >> 1)) ^ sx)) * 8 + (quad & 1) * 4;
            for (int df = 0; df < 4; ++df) {
                short4v va = *(const short4v*)(VtsC + (df * 16 + l16) * 64 + voff);
                o[df] = mfma_16x16x16_bf16(va, pb[kf], o[df]);
            }
        }
        __builtin_amdgcn_s_setprio(0);
        __syncthreads();
    }

    // epilogue: normalize by osum (all 4 regs identical), packed stores
    float inv = 1.0f / osum[0];
    unsigned short* yp = Y + ((size_t)b * T + qw + l16) * 1024 + h * 64 + quad * 4;
    for (int df = 0; df < 4; ++df) {
        uint2 pk;
        pk.x = pack_bf16x2(o[df][0] * inv, o[df][1] * inv);
        pk.y = pack_bf16x2(o[df][2] * inv, o[df][3] * inv);
        *(uint2*)(yp + df * 16) = pk;
    }
}

extern "C" void kernel_launch(void* const* d_in, const int* in_sizes, int n_in,
                              void* d_out, int out_size, void* d_ws, size_t ws_size,
                              hipStream_t stream) {
    const float* x = (const float*)d_in[0];
    const float* w_qkv = (const float*)d_in[1];
    const float* b_qkv = (const float*)d_in[2];
    const float* w_proj = (const float*)d_in[3];
    const float* b_proj = (const float*)d_in[4];
    float* out = (float*)d_out;

    // workspace carve (ushort elements)
    unsigned short* xbf = (unsigned short*)d_ws;        // 8192*1024
    unsigned short* wqkvt = xbf + 8388608;              // 3072*1024
    unsigned short* wprojt = wqkvt + 3145728;           // 1024*1024
    unsigned short* Qb = wprojt + 1048576;              // 64*2048*64
    unsigned short* Kb = Qb + 8388608;
    unsigned short* Vtb = Kb + 8388608;                 // V transposed [bh][d][t]
    unsigned short* Yb = Vtb + 8388608;

    hipLaunchKernelGGL(prep_kernel, dim3(9216), dim3(256), 0, stream,
                       x, (unsigned int*)xbf, w_qkv, wqkvt, w_proj, wprojt);
    hipLaunchKernelGGL(gemm_qkv, dim3(24, 32), dim3(512), 0, stream,
                       xbf, wqkvt, b_qkv, 8192, 3072, 1024,
                       Qb, Kb, Vtb);
    hipLaunchKernelGGL(attn_kernel, dim3(64, 32), dim3(256), 0, stream,
                       Qb, Kb, Vtb, Yb, 2048);
    hipLaunchKernelGGL(gemm_proj, dim3(8, 32), dim3(512), 0, stream,
                       Yb, wprojt, b_proj, 8192, 1024, 1024, out);
}

// Round 16
// 250.441 us; speedup vs baseline: 1.0127x; 1.0127x over previous
//
#include <hip/hip_runtime.h>
#include <hip/hip_bf16.h>
#include <stdint.h>

typedef __bf16 bf16_8 __attribute__((ext_vector_type(8)));
typedef float f32_4 __attribute__((ext_vector_type(4)));
typedef short short4v __attribute__((ext_vector_type(4)));

#define VMCNT(n) asm volatile("s_waitcnt vmcnt(" #n ")" ::: "memory")
#define SBAR __builtin_amdgcn_s_barrier()
#define SCHB __builtin_amdgcn_sched_barrier(0)

static __device__ __forceinline__ unsigned short f2bf(float f) {
    union { float f; unsigned int u; } v; v.f = f;
    unsigned int u = v.u;
    unsigned int r = (u + 0x7fffu + ((u >> 16) & 1u)) >> 16;
    return (unsigned short)r;
}

static __device__ __forceinline__ unsigned int pack_bf16x2(float a, float b) {
    union { float f; unsigned int u; } ua, ub;
    ua.f = a; ub.f = b;
    return __builtin_amdgcn_perm(ub.u + 0x8000u, ua.u + 0x8000u, 0x07060302u);
}

// 16x16x16 bf16 MFMA; B-operand layout == 16x16x32 C-layout (S^T feeds PV).
static __device__ __forceinline__ f32_4 mfma_16x16x16_bf16(short4v a, short4v b, f32_4 c) {
#if __has_builtin(__builtin_amdgcn_mfma_f32_16x16x16bf16_1k)
    return __builtin_amdgcn_mfma_f32_16x16x16bf16_1k(a, b, c, 0, 0, 0);
#else
    asm volatile("v_mfma_f32_16x16x16_bf16 %0, %1, %2, %0"
                 : "+v"(c) : "v"(a), "v"(b));
    return c;
#endif
}

// async global -> LDS, 16 B per lane (lds dest = wave-uniform base + lane*16)
static __device__ __forceinline__ void gll16(const unsigned short* g, unsigned short* l) {
    __builtin_amdgcn_global_load_lds(
        (const __attribute__((address_space(1))) unsigned int*)g,
        (__attribute__((address_space(3))) unsigned int*)l, 16, 0, 0);
}

// ---------------- fused prep: cvt x + transpose both weight matrices -------
__global__ __launch_bounds__(256) void prep_kernel(
    const float* __restrict__ x, unsigned int* __restrict__ xbf,
    const float* __restrict__ w_qkv, unsigned short* __restrict__ wqkvt,
    const float* __restrict__ w_proj, unsigned short* __restrict__ wprojt) {
    __shared__ unsigned short tile[64][65];
    int bid = blockIdx.x;
    if (bid < 8192) {
        int i = bid * 256 + threadIdx.x;
        float4 f = ((const float4*)x)[i];
        uint2 o;
        o.x = pack_bf16x2(f.x, f.y);
        o.y = pack_bf16x2(f.z, f.w);
        ((uint2*)xbf)[i] = o;
        return;
    }
    const float* in; unsigned short* out; int N, bx, by;
    if (bid < 8960) {
        in = w_qkv; out = wqkvt; N = 3072;
        int t = bid - 8192; bx = t % 48; by = t / 48;
    } else {
        in = w_proj; out = wprojt; N = 1024;
        int t = bid - 8960; bx = t & 15; by = t >> 4;
    }
    const int K = 1024;
    int k0 = by * 64, n0 = bx * 64;
    int tc = threadIdx.x & 63, tr = threadIdx.x >> 6;
    for (int p = 0; p < 16; ++p) {
        int k = p * 4 + tr;
        tile[k][tc] = f2bf(in[(size_t)(k0 + k) * N + n0 + tc]);
    }
    __syncthreads();
    for (int p = 0; p < 16; ++p) {
        int n = p * 4 + tr;
        out[(size_t)(n0 + n) * K + k0 + tc] = tile[tc][n];
    }
}

#define QSCALE 0.1803368801111204f  // 0.125 * log2(e)
#define BK 64

// ---------------- QKV GEMM: BM=256 BN=128 BK=64, 3-ring, 1 barrier/iter ----
// r13 verbatim (measured 65.5-72.5us across runs, 786 TF best).
__global__ __launch_bounds__(512) void gemm_qkv(
    const unsigned short* __restrict__ A,
    const unsigned short* __restrict__ Bt,
    const float* __restrict__ bias,
    int M, int N, int K,
    unsigned short* __restrict__ q_out, unsigned short* __restrict__ k_out,
    unsigned short* __restrict__ v_out) {
    __shared__ __align__(16) unsigned short As[3][256 * 64];
    __shared__ __align__(16) unsigned short Bs[3][128 * 64];
    int tid = threadIdx.x;
    int wave = tid >> 6, lane = tid & 63;
    int wm = wave >> 1, wn = wave & 1;
    int quad = lane >> 4, l16 = lane & 15;
    int m0 = blockIdx.y * 256, n0 = blockIdx.x * 128;
    int which = n0 >> 10;  // 0=Q 1=K 2=V

    f32_4 acc[4][4] = {};

    int srow = lane >> 3;                  // 0..7
    int scs = ((lane & 7) ^ srow) * 8;     // swizzled chunk elem offset
    const unsigned short* Ag = A + (size_t)(m0 + wave * 32 + srow) * K + scs;
    const unsigned short* Bg = Bt + (size_t)(n0 + wave * 16 + srow) * K + scs;
    int sx = l16 & 7;

    unsigned short *a0 = As[0], *a1 = As[1], *a2 = As[2];
    unsigned short *b0 = Bs[0], *b1 = Bs[1], *b2 = Bs[2];

#define STG_A(dst, kc) do { \
        for (int g = 0; g < 4; ++g) \
            gll16(Ag + (kc) + (size_t)(g * 8) * K, (dst) + (wave * 32 + g * 8) * 64); \
    } while (0)
#define STG_B(dst, kc) do { \
        for (int g = 0; g < 2; ++g) \
            gll16(Bg + (kc) + (size_t)(g * 8) * K, (dst) + (wave * 16 + g * 8) * 64); \
    } while (0)

    // prologue: stage tiles 0 and 1 (12 loads; tile0's 6 are the oldest)
    STG_A(a0, 0); STG_B(b0, 0);
    STG_A(a1, 64); STG_B(b1, 64);

    const int nkt = K >> 6;  // 16
    for (int kt = 0; kt < nkt; ++kt) {
        if (kt + 1 < nkt) { VMCNT(6); } else { VMCNT(0); }
        SCHB; SBAR; SCHB;   // single publish point per K-tile

        // ---- phase 0 (ks=0) ----
        bf16_8 af[4], bfr[4];
        for (int i = 0; i < 4; ++i)
            af[i] = *(const bf16_8*)(a0 + (wm * 64 + i * 16 + l16) * 64 +
                                     ((unsigned)(quad ^ sx)) * 8);
        for (int j = 0; j < 4; ++j)
            bfr[j] = *(const bf16_8*)(b0 + (wn * 64 + j * 16 + l16) * 64 +
                                      ((unsigned)(quad ^ sx)) * 8);
        if (kt + 2 < nkt) STG_A(a2, (kt + 2) * 64);
        __builtin_amdgcn_s_setprio(1);
        if (which < 2) {
            for (int i = 0; i < 4; ++i)
                for (int j = 0; j < 4; ++j)
                    acc[i][j] = __builtin_amdgcn_mfma_f32_16x16x32_bf16(bfr[j], af[i], acc[i][j], 0, 0, 0);
        } else {
            for (int i = 0; i < 4; ++i)
                for (int j = 0; j < 4; ++j)
                    acc[i][j] = __builtin_amdgcn_mfma_f32_16x16x32_bf16(af[i], bfr[j], acc[i][j], 0, 0, 0);
        }
        __builtin_amdgcn_s_setprio(0);

        // ---- phase 1 (ks=1) ----
        for (int i = 0; i < 4; ++i)
            af[i] = *(const bf16_8*)(a0 + (wm * 64 + i * 16 + l16) * 64 +
                                     ((unsigned)((4 + quad) ^ sx)) * 8);
        for (int j = 0; j < 4; ++j)
            bfr[j] = *(const bf16_8*)(b0 + (wn * 64 + j * 16 + l16) * 64 +
                                      ((unsigned)((4 + quad) ^ sx)) * 8);
        if (kt + 2 < nkt) STG_B(b2, (kt + 2) * 64);
        __builtin_amdgcn_s_setprio(1);
        if (which < 2) {
            for (int i = 0; i < 4; ++i)
                for (int j = 0; j < 4; ++j)
                    acc[i][j] = __builtin_amdgcn_mfma_f32_16x16x32_bf16(bfr[j], af[i], acc[i][j], 0, 0, 0);
        } else {
            for (int i = 0; i < 4; ++i)
                for (int j = 0; j < 4; ++j)
                    acc[i][j] = __builtin_amdgcn_mfma_f32_16x16x32_bf16(af[i], bfr[j], acc[i][j], 0, 0, 0);
        }
        __builtin_amdgcn_s_setprio(0);

        unsigned short* t;
        t = a0; a0 = a1; a1 = a2; a2 = t;
        t = b0; b0 = b1; b1 = b2; b2 = t;
    }
#undef STG_A
#undef STG_B

    int b = m0 >> 11;
    int tbase = (m0 & 2047) + wm * 64;
    int nw0 = n0 + wn * 64;
    if (which < 2) {
        unsigned short* dst = which == 0 ? q_out : k_out;
        float scale = which == 0 ? QSCALE : 1.0f;
        int h0 = ((n0 & 1023) >> 6) + wn;
        size_t base = ((size_t)((b << 4) + h0) * 2048) * 64;
        for (int j = 0; j < 4; ++j) {
            float4 b4 = *(const float4*)(bias + nw0 + j * 16 + quad * 4);
            int d0 = j * 16 + quad * 4;
            for (int i = 0; i < 4; ++i) {
                int t = tbase + i * 16 + l16;
                uint2 pk;
                pk.x = pack_bf16x2((acc[i][j][0] + b4.x) * scale,
                                   (acc[i][j][1] + b4.y) * scale);
                pk.y = pack_bf16x2((acc[i][j][2] + b4.z) * scale,
                                   (acc[i][j][3] + b4.w) * scale);
                *(uint2*)(dst + base + (size_t)t * 64 + d0) = pk;
            }
        }
    } else {
        for (int j = 0; j < 4; ++j) {
            int n = nw0 + j * 16 + l16;
            int c = n & 1023, h = c >> 6, d = c & 63;
            float bs = bias[n];
            size_t base = ((size_t)((b << 4) + h) * 64 + d) * 2048;
            for (int i = 0; i < 4; ++i) {
                int t0 = tbase + i * 16 + quad * 4;
                uint2 pk;
                pk.x = pack_bf16x2(acc[i][j][0] + bs, acc[i][j][1] + bs);
                pk.y = pack_bf16x2(acc[i][j][2] + bs, acc[i][j][3] + bs);
                *(uint2*)(v_out + base + t0) = pk;
            }
        }
    }
}

// ---------------- proj GEMM: BM=128 BN=128 BK=64, 2-phase dbuf (r2/r8/r13) -
// MEASURED-BEST proj: 512 blocks at 2 resident/CU. The 3-ring BM=256 port
// (r15) regressed ~17us — 256 blocks = exactly 1 block/CU with 147KB LDS
// leaves zero inter-block overlap; replicated r4-vs-r8. Shape beats schedule
// at proj's N=1024.
__global__ __launch_bounds__(256) void gemm_proj(
    const unsigned short* __restrict__ A,
    const unsigned short* __restrict__ Bt,
    const float* __restrict__ bias,
    int M, int N, int K, float* __restrict__ outf) {
    __shared__ __align__(16) unsigned short As[2][128 * BK];
    __shared__ __align__(16) unsigned short Bs[2][128 * BK];
    int tid = threadIdx.x;
    int wave = tid >> 6, lane = tid & 63;
    int wm = wave & 1, wn = wave >> 1;
    int quad = lane >> 4, l16 = lane & 15;
    int m0 = blockIdx.y * 128, n0 = blockIdx.x * 128;

    f32_4 acc[4][4] = {};

    int srow = lane >> 3;
    int scs = ((lane & 7) ^ srow) * 8;
    const unsigned short* Ag = A + (size_t)(m0 + wave * 32 + srow) * K + scs;
    const unsigned short* Bg = Bt + (size_t)(n0 + wave * 32 + srow) * K + scs;
    int sbase = wave * 32 * BK;
    int sx = l16 & 7;

    // prologue: stage tile 0 into buffer 0
    for (int p = 0; p < 4; ++p) {
        gll16(Ag + (size_t)(8 * p) * K, As[0] + sbase + p * 8 * BK);
        gll16(Bg + (size_t)(8 * p) * K, Bs[0] + sbase + p * 8 * BK);
    }
    __syncthreads();

    int cur = 0;
    for (int kt = 0; kt < K; kt += BK) {
        if (kt + BK < K) {
            int nxt = cur ^ 1;
            for (int p = 0; p < 4; ++p) {
                gll16(Ag + kt + BK + (size_t)(8 * p) * K, As[nxt] + sbase + p * 8 * BK);
                gll16(Bg + kt + BK + (size_t)(8 * p) * K, Bs[nxt] + sbase + p * 8 * BK);
            }
        }
        const unsigned short* Ac = As[cur];
        const unsigned short* Bc = Bs[cur];
        bf16_8 af[4][2], bfr[4][2];
        for (int i = 0; i < 4; ++i)
            for (int ks = 0; ks < 2; ++ks)
                af[i][ks] = *(const bf16_8*)(Ac + (wm * 64 + i * 16 + l16) * BK +
                                             ((unsigned)((ks * 4 + quad) ^ sx)) * 8);
        for (int j = 0; j < 4; ++j)
            for (int ks = 0; ks < 2; ++ks)
                bfr[j][ks] = *(const bf16_8*)(Bc + (wn * 64 + j * 16 + l16) * BK +
                                              ((unsigned)((ks * 4 + quad) ^ sx)) * 8);
        for (int i = 0; i < 4; ++i)
            for (int j = 0; j < 4; ++j) {
                acc[i][j] = __builtin_amdgcn_mfma_f32_16x16x32_bf16(af[i][0], bfr[j][0], acc[i][j], 0, 0, 0);
                acc[i][j] = __builtin_amdgcn_mfma_f32_16x16x32_bf16(af[i][1], bfr[j][1], acc[i][j], 0, 0, 0);
            }
        __syncthreads();
        cur ^= 1;
    }

    for (int j = 0; j < 4; ++j) {
        int n = n0 + wn * 64 + j * 16 + l16;
        float bs = bias[n];
        for (int i = 0; i < 4; ++i) {
            int m = m0 + wm * 64 + i * 16 + quad * 4;
            for (int r = 0; r < 4; ++r)
                outf[(size_t)(m + r) * N + n] = acc[i][j][r] + bs;
        }
    }
}

// ---------------- flash attention: single 64-row tile/block, 5 blocks/CU ---
// r8 + T5 setprio (ran+passed r9/r11/r12/r13/r15).
__global__ __launch_bounds__(256, 5) void attn_kernel(
    const unsigned short* __restrict__ Q, const unsigned short* __restrict__ Kb,
    const unsigned short* __restrict__ Vt, unsigned short* __restrict__ Y,
    int T) {
    __shared__ __align__(16) unsigned short KsB[2][64 * 64];
    __shared__ __align__(16) unsigned short VtsB[2][64 * 64];

    int tid = threadIdx.x;
    int wave = tid >> 6, lane = tid & 63;
    int quad = lane >> 4, l16 = lane & 15;
    int bh = blockIdx.x;
    int b = bh >> 4, h = bh & 15;
    int qt = 31 - blockIdx.y;
    int qw = qt * 64 + wave * 16;
    int nkt = qt + 1;

    int srow = lane >> 3;
    int scs = ((lane & 7) ^ srow) * 8;
    int sx = l16 & 7;

    // Q fragments: q = l16 (B-operand compatible), d = ks*32+quad*8
    bf16_8 qa[2];
    for (int ks = 0; ks < 2; ++ks)
        qa[ks] = *(const bf16_8*)(Q + ((size_t)bh * T + qw + l16) * 64 + ks * 32 + quad * 8);

    f32_4 o[4] = {};    // [df]: d = df*16+quad*4+r, q = l16
    f32_4 osum = {};    // lsum via ones-MFMA: all 4 regs identical
    short4v vones;
    { unsigned short one = 0x3F80;
      vones[0] = (short)one; vones[1] = (short)one; vones[2] = (short)one; vones[3] = (short)one; }

    // stage tile 0 into buffer 0 (async, swizzled)
    for (int p = 0; p < 2; ++p) {
        int row = wave * 16 + p * 8;
        gll16(Kb + ((size_t)bh * T + row + srow) * 64 + scs, &KsB[0][row * 64]);
        gll16(Vt + ((size_t)bh * 64 + row + srow) * (size_t)T + scs, &VtsB[0][row * 64]);
    }
    __syncthreads();

    for (int kt = 0; kt < nkt; ++kt) {
        int cur = kt & 1;
        int kb = kt * 64;
        if (kt + 1 < nkt) {
            int kb2 = kb + 64, nxt = cur ^ 1;
            for (int p = 0; p < 2; ++p) {
                int row = wave * 16 + p * 8;
                gll16(Kb + ((size_t)bh * T + kb2 + row + srow) * 64 + scs, &KsB[nxt][row * 64]);
                gll16(Vt + ((size_t)bh * 64 + row + srow) * (size_t)T + kb2 + scs, &VtsB[nxt][row * 64]);
            }
        }
        const unsigned short* KsC = KsB[cur];
        const unsigned short* VtsC = VtsB[cur];

        // S^T = K @ Q^T : lane holds (k = kf*16+quad*4+r, q = l16)
        f32_4 s[4] = {};
        __builtin_amdgcn_s_setprio(1);
        for (int kf = 0; kf < 4; ++kf) {
            bf16_8 k0 = *(const bf16_8*)(KsC + (kf * 16 + l16) * 64 + ((unsigned)(quad ^ sx)) * 8);
            bf16_8 k1 = *(const bf16_8*)(KsC + (kf * 16 + l16) * 64 + ((unsigned)((4 + quad) ^ sx)) * 8);
            s[kf] = __builtin_amdgcn_mfma_f32_16x16x32_bf16(k0, qa[0], s[kf], 0, 0, 0);
            s[kf] = __builtin_amdgcn_mfma_f32_16x16x32_bf16(k1, qa[1], s[kf], 0, 0, 0);
        }
        __builtin_amdgcn_s_setprio(0);

        // causal mask (diagonal tile only)
        if (kt == qt) {
            int q = qw + l16;
            for (int kf = 0; kf < 4; ++kf) {
                int kk = kb + kf * 16 + quad * 4;
                for (int r = 0; r < 4; ++r)
                    if (kk + r > q) s[kf][r] = -1e30f;
            }
        }

        // no-max softmax: p = 2^s, packed in-register to PV B-operands
        short4v pb[4];
        for (int kf = 0; kf < 4; ++kf) {
            float p0 = __builtin_amdgcn_exp2f(s[kf][0]);
            float p1 = __builtin_amdgcn_exp2f(s[kf][1]);
            float p2 = __builtin_amdgcn_exp2f(s[kf][2]);
            float p3 = __builtin_amdgcn_exp2f(s[kf][3]);
            union { unsigned int u[2]; short4v s4; } pu;
            pu.u[0] = pack_bf16x2(p0, p1);
            pu.u[1] = pack_bf16x2(p2, p3);
            pb[kf] = pu.s4;
        }

        // PV + lsum: o[df] += V^T@P^T ; osum += 1@P^T (rowsum, no shuffles)
        __builtin_amdgcn_s_setprio(1);
        for (int kf = 0; kf < 4; ++kf) {
            osum = mfma_16x16x16_bf16(vones, pb[kf], osum);
            unsigned voff = ((unsigned)((2 * kf + (quad >> 1)) ^ sx)) * 8 + (quad & 1) * 4;
            for (int df = 0; df < 4; ++df) {
                short4v va = *(const short4v*)(VtsC + (df * 16 + l16) * 64 + voff);
                o[df] = mfma_16x16x16_bf16(va, pb[kf], o[df]);
            }
        }
        __builtin_amdgcn_s_setprio(0);
        __syncthreads();
    }

    // epilogue: normalize by osum (all 4 regs identical), packed stores
    float inv = 1.0f / osum[0];
    unsigned short* yp = Y + ((size_t)b * T + qw + l16) * 1024 + h * 64 + quad * 4;
    for (int df = 0; df < 4; ++df) {
        uint2 pk;
        pk.x = pack_bf16x2(o[df][0] * inv, o[df][1] * inv);
        pk.y = pack_bf16x2(o[df][2] * inv, o[df][3] * inv);
        *(uint2*)(yp + df * 16) = pk;
    }
}

extern "C" void kernel_launch(void* const* d_in, const int* in_sizes, int n_in,
                              void* d_out, int out_size, void* d_ws, size_t ws_size,
                              hipStream_t stream) {
    const float* x = (const float*)d_in[0];
    const float* w_qkv = (const float*)d_in[1];
    const float* b_qkv = (const float*)d_in[2];
    const float* w_proj = (const float*)d_in[3];
    const float* b_proj = (const float*)d_in[4];
    float* out = (float*)d_out;

    // workspace carve (ushort elements)
    unsigned short* xbf = (unsigned short*)d_ws;        // 8192*1024
    unsigned short* wqkvt = xbf + 8388608;              // 3072*1024
    unsigned short* wprojt = wqkvt + 3145728;           // 1024*1024
    unsigned short* Qb = wprojt + 1048576;              // 64*2048*64
    unsigned short* Kb = Qb + 8388608;
    unsigned short* Vtb = Kb + 8388608;                 // V transposed [bh][d][t]
    unsigned short* Yb = Vtb + 8388608;

    hipLaunchKernelGGL(prep_kernel, dim3(9216), dim3(256), 0, stream,
                       x, (unsigned int*)xbf, w_qkv, wqkvt, w_proj, wprojt);
    hipLaunchKernelGGL(gemm_qkv, dim3(24, 32), dim3(512), 0, stream,
                       xbf, wqkvt, b_qkv, 8192, 3072, 1024,
                       Qb, Kb, Vtb);
    hipLaunchKernelGGL(attn_kernel, dim3(64, 32), dim3(256), 0, stream,
                       Qb, Kb, Vtb, Yb, 2048);
    hipLaunchKernelGGL(gemm_proj, dim3(8, 64), dim3(256), 0, stream,
                       Yb, wprojt, b_proj, 8192, 1024, 1024, out);
}

// Round 17
// 234.050 us; speedup vs baseline: 1.0836x; 1.0700x over previous
//
#include <hip/hip_runtime.h>
#include <hip/hip_bf16.h>
#include <stdint.h>

typedef __bf16 bf16_8 __attribute__((ext_vector_type(8)));
typedef float f32_4 __attribute__((ext_vector_type(4)));
typedef short short4v __attribute__((ext_vector_type(4)));

#define VMCNT(n) asm volatile("s_waitcnt vmcnt(" #n ")" ::: "memory")
#define SBAR __builtin_amdgcn_s_barrier()
#define SCHB __builtin_amdgcn_sched_barrier(0)

static __device__ __forceinline__ unsigned short f2bf(float f) {
    union { float f; unsigned int u; } v; v.f = f;
    unsigned int u = v.u;
    unsigned int r = (u + 0x7fffu + ((u >> 16) & 1u)) >> 16;
    return (unsigned short)r;
}

static __device__ __forceinline__ unsigned int pack_bf16x2(float a, float b) {
    union { float f; unsigned int u; } ua, ub;
    ua.f = a; ub.f = b;
    return __builtin_amdgcn_perm(ub.u + 0x8000u, ua.u + 0x8000u, 0x07060302u);
}

// 16x16x16 bf16 MFMA; B-operand layout == 16x16x32 C-layout (S^T feeds PV).
static __device__ __forceinline__ f32_4 mfma_16x16x16_bf16(short4v a, short4v b, f32_4 c) {
#if __has_builtin(__builtin_amdgcn_mfma_f32_16x16x16bf16_1k)
    return __builtin_amdgcn_mfma_f32_16x16x16bf16_1k(a, b, c, 0, 0, 0);
#else
    asm volatile("v_mfma_f32_16x16x16_bf16 %0, %1, %2, %0"
                 : "+v"(c) : "v"(a), "v"(b));
    return c;
#endif
}

// async global -> LDS, 16 B per lane (lds dest = wave-uniform base + lane*16)
static __device__ __forceinline__ void gll16(const unsigned short* g, unsigned short* l) {
    __builtin_amdgcn_global_load_lds(
        (const __attribute__((address_space(1))) unsigned int*)g,
        (__attribute__((address_space(3))) unsigned int*)l, 16, 0, 0);
}

// ---------------- fused prep: cvt x + transpose both weight matrices -------
__global__ __launch_bounds__(256) void prep_kernel(
    const float* __restrict__ x, unsigned int* __restrict__ xbf,
    const float* __restrict__ w_qkv, unsigned short* __restrict__ wqkvt,
    const float* __restrict__ w_proj, unsigned short* __restrict__ wprojt) {
    __shared__ unsigned short tile[64][65];
    int bid = blockIdx.x;
    if (bid < 8192) {
        int i = bid * 256 + threadIdx.x;
        float4 f = ((const float4*)x)[i];
        uint2 o;
        o.x = pack_bf16x2(f.x, f.y);
        o.y = pack_bf16x2(f.z, f.w);
        ((uint2*)xbf)[i] = o;
        return;
    }
    const float* in; unsigned short* out; int N, bx, by;
    if (bid < 8960) {
        in = w_qkv; out = wqkvt; N = 3072;
        int t = bid - 8192; bx = t % 48; by = t / 48;
    } else {
        in = w_proj; out = wprojt; N = 1024;
        int t = bid - 8960; bx = t & 15; by = t >> 4;
    }
    const int K = 1024;
    int k0 = by * 64, n0 = bx * 64;
    int tc = threadIdx.x & 63, tr = threadIdx.x >> 6;
    for (int p = 0; p < 16; ++p) {
        int k = p * 4 + tr;
        tile[k][tc] = f2bf(in[(size_t)(k0 + k) * N + n0 + tc]);
    }
    __syncthreads();
    for (int p = 0; p < 16; ++p) {
        int n = p * 4 + tr;
        out[(size_t)(n0 + n) * K + k0 + tc] = tile[tc][n];
    }
}

#define QSCALE 0.1803368801111204f  // 0.125 * log2(e)
#define BK 64

// ---------------- QKV GEMM: BM=256 BN=128 BK=64, 3-ring, 1 barrier/iter ----
// Session-best structure (65.5-72.5us, 786 TF best). Structural ceiling at
// this geometry: 64x64 wave tile -> LDS read+write ~1900 cyc of the 3280-cyc
// per-CU K-tile budget at 1 resident block; the acc[8][4] escape is blocked
// by the toolchain's 128-VGPR allocation for 512-thread kernels (3 attempts,
// all spilled ~470MB scratch).
__global__ __launch_bounds__(512) void gemm_qkv(
    const unsigned short* __restrict__ A,
    const unsigned short* __restrict__ Bt,
    const float* __restrict__ bias,
    int M, int N, int K,
    unsigned short* __restrict__ q_out, unsigned short* __restrict__ k_out,
    unsigned short* __restrict__ v_out) {
    __shared__ __align__(16) unsigned short As[3][256 * 64];
    __shared__ __align__(16) unsigned short Bs[3][128 * 64];
    int tid = threadIdx.x;
    int wave = tid >> 6, lane = tid & 63;
    int wm = wave >> 1, wn = wave & 1;
    int quad = lane >> 4, l16 = lane & 15;
    int m0 = blockIdx.y * 256, n0 = blockIdx.x * 128;
    int which = n0 >> 10;  // 0=Q 1=K 2=V

    f32_4 acc[4][4] = {};

    int srow = lane >> 3;                  // 0..7
    int scs = ((lane & 7) ^ srow) * 8;     // swizzled chunk elem offset
    const unsigned short* Ag = A + (size_t)(m0 + wave * 32 + srow) * K + scs;
    const unsigned short* Bg = Bt + (size_t)(n0 + wave * 16 + srow) * K + scs;
    int sx = l16 & 7;

    unsigned short *a0 = As[0], *a1 = As[1], *a2 = As[2];
    unsigned short *b0 = Bs[0], *b1 = Bs[1], *b2 = Bs[2];

#define STG_A(dst, kc) do { \
        for (int g = 0; g < 4; ++g) \
            gll16(Ag + (kc) + (size_t)(g * 8) * K, (dst) + (wave * 32 + g * 8) * 64); \
    } while (0)
#define STG_B(dst, kc) do { \
        for (int g = 0; g < 2; ++g) \
            gll16(Bg + (kc) + (size_t)(g * 8) * K, (dst) + (wave * 16 + g * 8) * 64); \
    } while (0)

    // prologue: stage tiles 0 and 1 (12 loads; tile0's 6 are the oldest)
    STG_A(a0, 0); STG_B(b0, 0);
    STG_A(a1, 64); STG_B(b1, 64);

    const int nkt = K >> 6;  // 16
    for (int kt = 0; kt < nkt; ++kt) {
        if (kt + 1 < nkt) { VMCNT(6); } else { VMCNT(0); }
        SCHB; SBAR; SCHB;   // single publish point per K-tile

        // ---- phase 0 (ks=0) ----
        bf16_8 af[4], bfr[4];
        for (int i = 0; i < 4; ++i)
            af[i] = *(const bf16_8*)(a0 + (wm * 64 + i * 16 + l16) * 64 +
                                     ((unsigned)(quad ^ sx)) * 8);
        for (int j = 0; j < 4; ++j)
            bfr[j] = *(const bf16_8*)(b0 + (wn * 64 + j * 16 + l16) * 64 +
                                      ((unsigned)(quad ^ sx)) * 8);
        if (kt + 2 < nkt) STG_A(a2, (kt + 2) * 64);
        __builtin_amdgcn_s_setprio(1);
        if (which < 2) {
            for (int i = 0; i < 4; ++i)
                for (int j = 0; j < 4; ++j)
                    acc[i][j] = __builtin_amdgcn_mfma_f32_16x16x32_bf16(bfr[j], af[i], acc[i][j], 0, 0, 0);
        } else {
            for (int i = 0; i < 4; ++i)
                for (int j = 0; j < 4; ++j)
                    acc[i][j] = __builtin_amdgcn_mfma_f32_16x16x32_bf16(af[i], bfr[j], acc[i][j], 0, 0, 0);
        }
        __builtin_amdgcn_s_setprio(0);

        // ---- phase 1 (ks=1) ----
        for (int i = 0; i < 4; ++i)
            af[i] = *(const bf16_8*)(a0 + (wm * 64 + i * 16 + l16) * 64 +
                                     ((unsigned)((4 + quad) ^ sx)) * 8);
        for (int j = 0; j < 4; ++j)
            bfr[j] = *(const bf16_8*)(b0 + (wn * 64 + j * 16 + l16) * 64 +
                                      ((unsigned)((4 + quad) ^ sx)) * 8);
        if (kt + 2 < nkt) STG_B(b2, (kt + 2) * 64);
        __builtin_amdgcn_s_setprio(1);
        if (which < 2) {
            for (int i = 0; i < 4; ++i)
                for (int j = 0; j < 4; ++j)
                    acc[i][j] = __builtin_amdgcn_mfma_f32_16x16x32_bf16(bfr[j], af[i], acc[i][j], 0, 0, 0);
        } else {
            for (int i = 0; i < 4; ++i)
                for (int j = 0; j < 4; ++j)
                    acc[i][j] = __builtin_amdgcn_mfma_f32_16x16x32_bf16(af[i], bfr[j], acc[i][j], 0, 0, 0);
        }
        __builtin_amdgcn_s_setprio(0);

        unsigned short* t;
        t = a0; a0 = a1; a1 = a2; a2 = t;
        t = b0; b0 = b1; b1 = b2; b2 = t;
    }
#undef STG_A
#undef STG_B

    int b = m0 >> 11;
    int tbase = (m0 & 2047) + wm * 64;
    int nw0 = n0 + wn * 64;
    if (which < 2) {
        unsigned short* dst = which == 0 ? q_out : k_out;
        float scale = which == 0 ? QSCALE : 1.0f;
        int h0 = ((n0 & 1023) >> 6) + wn;
        size_t base = ((size_t)((b << 4) + h0) * 2048) * 64;
        for (int j = 0; j < 4; ++j) {
            float4 b4 = *(const float4*)(bias + nw0 + j * 16 + quad * 4);
            int d0 = j * 16 + quad * 4;
            for (int i = 0; i < 4; ++i) {
                int t = tbase + i * 16 + l16;
                uint2 pk;
                pk.x = pack_bf16x2((acc[i][j][0] + b4.x) * scale,
                                   (acc[i][j][1] + b4.y) * scale);
                pk.y = pack_bf16x2((acc[i][j][2] + b4.z) * scale,
                                   (acc[i][j][3] + b4.w) * scale);
                *(uint2*)(dst + base + (size_t)t * 64 + d0) = pk;
            }
        }
    } else {
        for (int j = 0; j < 4; ++j) {
            int n = nw0 + j * 16 + l16;
            int c = n & 1023, h = c >> 6, d = c & 63;
            float bs = bias[n];
            size_t base = ((size_t)((b << 4) + h) * 64 + d) * 2048;
            for (int i = 0; i < 4; ++i) {
                int t0 = tbase + i * 16 + quad * 4;
                uint2 pk;
                pk.x = pack_bf16x2(acc[i][j][0] + bs, acc[i][j][1] + bs);
                pk.y = pack_bf16x2(acc[i][j][2] + bs, acc[i][j][3] + bs);
                *(uint2*)(v_out + base + t0) = pk;
            }
        }
    }
}

// ---------------- proj GEMM: BM=128 BN=128 BK=64, 2-phase dbuf -------------
// MEASURED-BEST proj: 512 blocks at 2 resident/CU. The 3-ring BM=256 port
// regressed ~17us twice (1 block/CU, zero inter-block overlap at N=1024).
__global__ __launch_bounds__(256) void gemm_proj(
    const unsigned short* __restrict__ A,
    const unsigned short* __restrict__ Bt,
    const float* __restrict__ bias,
    int M, int N, int K, float* __restrict__ outf) {
    __shared__ __align__(16) unsigned short As[2][128 * BK];
    __shared__ __align__(16) unsigned short Bs[2][128 * BK];
    int tid = threadIdx.x;
    int wave = tid >> 6, lane = tid & 63;
    int wm = wave & 1, wn = wave >> 1;
    int quad = lane >> 4, l16 = lane & 15;
    int m0 = blockIdx.y * 128, n0 = blockIdx.x * 128;

    f32_4 acc[4][4] = {};

    int srow = lane >> 3;
    int scs = ((lane & 7) ^ srow) * 8;
    const unsigned short* Ag = A + (size_t)(m0 + wave * 32 + srow) * K + scs;
    const unsigned short* Bg = Bt + (size_t)(n0 + wave * 32 + srow) * K + scs;
    int sbase = wave * 32 * BK;
    int sx = l16 & 7;

    // prologue: stage tile 0 into buffer 0
    for (int p = 0; p < 4; ++p) {
        gll16(Ag + (size_t)(8 * p) * K, As[0] + sbase + p * 8 * BK);
        gll16(Bg + (size_t)(8 * p) * K, Bs[0] + sbase + p * 8 * BK);
    }
    __syncthreads();

    int cur = 0;
    for (int kt = 0; kt < K; kt += BK) {
        if (kt + BK < K) {
            int nxt = cur ^ 1;
            for (int p = 0; p < 4; ++p) {
                gll16(Ag + kt + BK + (size_t)(8 * p) * K, As[nxt] + sbase + p * 8 * BK);
                gll16(Bg + kt + BK + (size_t)(8 * p) * K, Bs[nxt] + sbase + p * 8 * BK);
            }
        }
        const unsigned short* Ac = As[cur];
        const unsigned short* Bc = Bs[cur];
        bf16_8 af[4][2], bfr[4][2];
        for (int i = 0; i < 4; ++i)
            for (int ks = 0; ks < 2; ++ks)
                af[i][ks] = *(const bf16_8*)(Ac + (wm * 64 + i * 16 + l16) * BK +
                                             ((unsigned)((ks * 4 + quad) ^ sx)) * 8);
        for (int j = 0; j < 4; ++j)
            for (int ks = 0; ks < 2; ++ks)
                bfr[j][ks] = *(const bf16_8*)(Bc + (wn * 64 + j * 16 + l16) * BK +
                                              ((unsigned)((ks * 4 + quad) ^ sx)) * 8);
        for (int i = 0; i < 4; ++i)
            for (int j = 0; j < 4; ++j) {
                acc[i][j] = __builtin_amdgcn_mfma_f32_16x16x32_bf16(af[i][0], bfr[j][0], acc[i][j], 0, 0, 0);
                acc[i][j] = __builtin_amdgcn_mfma_f32_16x16x32_bf16(af[i][1], bfr[j][1], acc[i][j], 0, 0, 0);
            }
        __syncthreads();
        cur ^= 1;
    }

    for (int j = 0; j < 4; ++j) {
        int n = n0 + wn * 64 + j * 16 + l16;
        float bs = bias[n];
        for (int i = 0; i < 4; ++i) {
            int m = m0 + wm * 64 + i * 16 + quad * 4;
            for (int r = 0; r < 4; ++r)
                outf[(size_t)(m + r) * N + n] = acc[i][j][r] + bs;
        }
    }
}

// ---------------- flash attention: single 64-row tile/block, 5 blocks/CU ---
// r8 + T5 setprio (ran+passed r9/r11/r12/r13/r15/r16).
__global__ __launch_bounds__(256, 5) void attn_kernel(
    const unsigned short* __restrict__ Q, const unsigned short* __restrict__ Kb,
    const unsigned short* __restrict__ Vt, unsigned short* __restrict__ Y,
    int T) {
    __shared__ __align__(16) unsigned short KsB[2][64 * 64];
    __shared__ __align__(16) unsigned short VtsB[2][64 * 64];

    int tid = threadIdx.x;
    int wave = tid >> 6, lane = tid & 63;
    int quad = lane >> 4, l16 = lane & 15;
    int bh = blockIdx.x;
    int b = bh >> 4, h = bh & 15;
    int qt = 31 - blockIdx.y;
    int qw = qt * 64 + wave * 16;
    int nkt = qt + 1;

    int srow = lane >> 3;
    int scs = ((lane & 7) ^ srow) * 8;
    int sx = l16 & 7;

    // Q fragments: q = l16 (B-operand compatible), d = ks*32+quad*8
    bf16_8 qa[2];
    for (int ks = 0; ks < 2; ++ks)
        qa[ks] = *(const bf16_8*)(Q + ((size_t)bh * T + qw + l16) * 64 + ks * 32 + quad * 8);

    f32_4 o[4] = {};    // [df]: d = df*16+quad*4+r, q = l16
    f32_4 osum = {};    // lsum via ones-MFMA: all 4 regs identical
    short4v vones;
    { unsigned short one = 0x3F80;
      vones[0] = (short)one; vones[1] = (short)one; vones[2] = (short)one; vones[3] = (short)one; }

    // stage tile 0 into buffer 0 (async, swizzled)
    for (int p = 0; p < 2; ++p) {
        int row = wave * 16 + p * 8;
        gll16(Kb + ((size_t)bh * T + row + srow) * 64 + scs, &KsB[0][row * 64]);
        gll16(Vt + ((size_t)bh * 64 + row + srow) * (size_t)T + scs, &VtsB[0][row * 64]);
    }
    __syncthreads();

    for (int kt = 0; kt < nkt; ++kt) {
        int cur = kt & 1;
        int kb = kt * 64;
        if (kt + 1 < nkt) {
            int kb2 = kb + 64, nxt = cur ^ 1;
            for (int p = 0; p < 2; ++p) {
                int row = wave * 16 + p * 8;
                gll16(Kb + ((size_t)bh * T + kb2 + row + srow) * 64 + scs, &KsB[nxt][row * 64]);
                gll16(Vt + ((size_t)bh * 64 + row + srow) * (size_t)T + kb2 + scs, &VtsB[nxt][row * 64]);
            }
        }
        const unsigned short* KsC = KsB[cur];
        const unsigned short* VtsC = VtsB[cur];

        // S^T = K @ Q^T : lane holds (k = kf*16+quad*4+r, q = l16)
        f32_4 s[4] = {};
        __builtin_amdgcn_s_setprio(1);
        for (int kf = 0; kf < 4; ++kf) {
            bf16_8 k0 = *(const bf16_8*)(KsC + (kf * 16 + l16) * 64 + ((unsigned)(quad ^ sx)) * 8);
            bf16_8 k1 = *(const bf16_8*)(KsC + (kf * 16 + l16) * 64 + ((unsigned)((4 + quad) ^ sx)) * 8);
            s[kf] = __builtin_amdgcn_mfma_f32_16x16x32_bf16(k0, qa[0], s[kf], 0, 0, 0);
            s[kf] = __builtin_amdgcn_mfma_f32_16x16x32_bf16(k1, qa[1], s[kf], 0, 0, 0);
        }
        __builtin_amdgcn_s_setprio(0);

        // causal mask (diagonal tile only)
        if (kt == qt) {
            int q = qw + l16;
            for (int kf = 0; kf < 4; ++kf) {
                int kk = kb + kf * 16 + quad * 4;
                for (int r = 0; r < 4; ++r)
                    if (kk + r > q) s[kf][r] = -1e30f;
            }
        }

        // no-max softmax: p = 2^s, packed in-register to PV B-operands
        short4v pb[4];
        for (int kf = 0; kf < 4; ++kf) {
            float p0 = __builtin_amdgcn_exp2f(s[kf][0]);
            float p1 = __builtin_amdgcn_exp2f(s[kf][1]);
            float p2 = __builtin_amdgcn_exp2f(s[kf][2]);
            float p3 = __builtin_amdgcn_exp2f(s[kf][3]);
            union { unsigned int u[2]; short4v s4; } pu;
            pu.u[0] = pack_bf16x2(p0, p1);
            pu.u[1] = pack_bf16x2(p2, p3);
            pb[kf] = pu.s4;
        }

        // PV + lsum: o[df] += V^T@P^T ; osum += 1@P^T (rowsum, no shuffles)
        __builtin_amdgcn_s_setprio(1);
        for (int kf = 0; kf < 4; ++kf) {
            osum = mfma_16x16x16_bf16(vones, pb[kf], osum);
            unsigned voff = ((unsigned)((2 * kf + (quad >> 1)) ^ sx)) * 8 + (quad & 1) * 4;
            for (int df = 0; df < 4; ++df) {
                short4v va = *(const short4v*)(VtsC + (df * 16 + l16) * 64 + voff);
                o[df] = mfma_16x16x16_bf16(va, pb[kf], o[df]);
            }
        }
        __builtin_amdgcn_s_setprio(0);
        __syncthreads();
    }

    // epilogue: normalize by osum (all 4 regs identical), packed stores
    float inv = 1.0f / osum[0];
    unsigned short* yp = Y + ((size_t)b * T + qw + l16) * 1024 + h * 64 + quad * 4;
    for (int df = 0; df < 4; ++df) {
        uint2 pk;
        pk.x = pack_bf16x2(o[df][0] * inv, o[df][1] * inv);
        pk.y = pack_bf16x2(o[df][2] * inv, o[df][3] * inv);
        *(uint2*)(yp + df * 16) = pk;
    }
}

extern "C" void kernel_launch(void* const* d_in, const int* in_sizes, int n_in,
                              void* d_out, int out_size, void* d_ws, size_t ws_size,
                              hipStream_t stream) {
    const float* x = (const float*)d_in[0];
    const float* w_qkv = (const float*)d_in[1];
    const float* b_qkv = (const float*)d_in[2];
    const float* w_proj = (const float*)d_in[3];
    const float* b_proj = (const float*)d_in[4];
    float* out = (float*)d_out;

    // workspace carve (ushort elements)
    unsigned short* xbf = (unsigned short*)d_ws;        // 8192*1024
    unsigned short* wqkvt = xbf + 8388608;              // 3072*1024
    unsigned short* wprojt = wqkvt + 3145728;           // 1024*1024
    unsigned short* Qb = wprojt + 1048576;              // 64*2048*64
    unsigned short* Kb = Qb + 8388608;
    unsigned short* Vtb = Kb + 8388608;                 // V transposed [bh][d][t]
    unsigned short* Yb = Vtb + 8388608;

    hipLaunchKernelGGL(prep_kernel, dim3(9216), dim3(256), 0, stream,
                       x, (unsigned int*)xbf, w_qkv, wqkvt, w_proj, wprojt);
    hipLaunchKernelGGL(gemm_qkv, dim3(24, 32), dim3(512), 0, stream,
                       xbf, wqkvt, b_qkv, 8192, 3072, 1024,
                       Qb, Kb, Vtb);
    hipLaunchKernelGGL(attn_kernel, dim3(64, 32), dim3(256), 0, stream,
                       Qb, Kb, Vtb, Yb, 2048);
    hipLaunchKernelGGL(gemm_proj, dim3(8, 64), dim3(256), 0, stream,
                       Yb, wprojt, b_proj, 8192, 1024, 1024, out);
}